// Round 20
// baseline (2662.497 us; speedup 1.0000x reference)
//
#include <hip/hip_runtime.h>

#define E_CNT 32768
#define V_CNT 98304
#define D_ 128
#define VOCAB_ 2000
#define ITERS_ 6

typedef unsigned short u16;
typedef unsigned int u32;
typedef _Float16 f16;
typedef __attribute__((ext_vector_type(8))) _Float16 f16x8;
typedef __attribute__((ext_vector_type(4))) float f32x4;

__device__ __forceinline__ f32x4 MFh(f16x8 a, f16x8 b, f32x4 c) {
    return __builtin_amdgcn_mfma_f32_16x16x32_f16(a, b, c, 0, 0, 0);
}
__device__ __forceinline__ float sigmoid_f(float x) {
    return __builtin_amdgcn_rcpf(1.0f + __expf(-x));
}
__device__ __forceinline__ float tanh_f(float x) {
    return fmaf(2.0f, __builtin_amdgcn_rcpf(1.0f + __expf(-2.0f * x)), -1.0f);
}
__device__ __forceinline__ u16 f16bits(f16 h) {
    union { f16 f; u16 u; } cv; cv.f = h; return cv.u;
}
__device__ __forceinline__ f16 bits2f16(u16 u) {
    union { f16 f; u16 u; } cv; cv.u = u; return cv.f;
}

__global__ void detect_mask_kernel(const unsigned int* __restrict__ m, int* __restrict__ flag) {
    int i = blockIdx.x * 256 + threadIdx.x;
    if (i < 4096 && m[i] > 1u) atomicOr(flag, 1);
}

// Pack weights into MFMA fragment order.
// WvF (fp16): [nt(32)][kk(16)][lane(64)][8]  j = nt*16+(l&15), k = kk*32+(l>>4)*8+r
// WeF (fp16): [p(3)][nt(32)][kk(8)][64][8]
// OwF (fp16, single term): [nt(125)][kk(4)][64][8]
__global__ void prep_kernel(
    const float* __restrict__ Wih_v2e, const float* __restrict__ Whh_v2e,
    const float* __restrict__ bih_v2e, const float* __restrict__ bhh_v2e,
    const float* __restrict__ Wih_e2v, const float* __restrict__ Whh_e2v,
    const float* __restrict__ bih_e2v, const float* __restrict__ bhh_e2v,
    const float* __restrict__ out_w,
    f16* __restrict__ WvF, f16* __restrict__ WeF, f16* __restrict__ OwF,
    float* __restrict__ bv, float* __restrict__ be)
{
    int idx = blockIdx.x * 256 + threadIdx.x;
    if (idx < 262144) {
        const int r = idx & 7, l = (idx >> 3) & 63, t = idx >> 9;
        const int kk = t & 15, nt = t >> 4;
        const int j = nt * 16 + (l & 15);
        const int k = kk * 32 + (l >> 4) * 8 + r;
        const float w = (k < 384) ? Wih_v2e[j * 384 + k] : Whh_v2e[j * 128 + (k - 384)];
        WvF[idx] = (f16)w;
        return;
    }
    idx -= 262144;
    if (idx < 393216) {
        const int r = idx & 7, l = (idx >> 3) & 63, t = idx >> 9;  // t < 768
        const int kk = t & 7, nt = (t >> 3) & 31, p = t >> 8;
        const int j = nt * 16 + (l & 15);
        const int k = kk * 32 + (l >> 4) * 8 + r;
        const float w = (k < 128) ? Wih_e2v[(p * 512 + j) * 128 + k]
                                  : Whh_e2v[(p * 512 + j) * 128 + (k - 128)];
        WeF[idx] = (f16)w;
        return;
    }
    idx -= 393216;
    if (idx < 256000) {
        const int r = idx & 7, l = (idx >> 3) & 63, t = idx >> 9;  // t < 500
        const int kk = t & 3, nt = t >> 2;
        const int j = nt * 16 + (l & 15);
        const int k = kk * 32 + (l >> 4) * 8 + r;
        OwF[idx] = (f16)out_w[j * 128 + k];
        return;
    }
    idx -= 256000;
    if (idx < 512) { bv[idx] = bih_v2e[idx] + bhh_v2e[idx]; return; }
    idx -= 512;
    if (idx < 1536) { be[idx] = bih_e2v[idx] + bhh_e2v[idx]; return; }
}

// Persistent iteration kernel: 512 thr / 8 waves / 32 edges / all 6 iterations.
// r20: (1) EXPANDED phases -> all LDS offsets compile-time immediates (r18's unified
// loop made them runtime selects: VALUBusy 48%); (2) c_v ENTIRELY IN REGISTERS
// (24 VGPR at mt=2) -> cvG4 deleted, -577 MB traffic, cell is pure reg VALU;
// (3) hold-h: e2v = 3 pure-read GEMMs back-to-back, cells hold packed h in 12 u32
// (all-constant indices via macro expansion - r16's scratch trap avoided),
// ONE WAR barrier, masked HV writes -> 4 barriers/iter.
// LDS 56 KB (24K HV + 8K HE + 24K pad): 2 blocks/CU model -> honest 128-VGPR budget
// (live ~110); 16 waves/CU.
__global__ __launch_bounds__(512)
void fused_kernel(
    const int* __restrict__ x_v,
    const float* __restrict__ emb,
    const float* __restrict__ eiw, const float* __restrict__ eib,
    const f16* __restrict__ WvF, const f16* __restrict__ WeF,
    const float* __restrict__ bv, const float* __restrict__ be,
    const void* __restrict__ mask, const int* __restrict__ flagp,
    f16* __restrict__ hvOut)
{
    __shared__ f16 HV[12288];     // 24 KB [mt(2)*12+kk][lane][8]
    __shared__ f16 HE[4096];      //  8 KB [mt(2)*4+kk][lane][8]
    __shared__ char PADL[24576];  // 24 KB occupancy governor -> 2 blocks/CU

    const int tid = threadIdx.x;
    const int c = tid >> 6, l = tid & 63;
    const int lr = l & 15, lk = l >> 4;
    const int e0 = blockIdx.x * 32;

    PADL[tid] = (char)tid;

    // ---- init h_v from embeddings
    for (int i = tid; i < 32 * 48; i += 512) {
        const int row = i / 48, seg = i % 48;
        int id = x_v[(e0 + row) * 3 + (seg >> 4)];
        if (id < 0 || id > VOCAB_) id = VOCAB_;
        const float* s = emb + id * D_ + ((seg * 8) & 127);
        float4 a = *(const float4*)s, b = *(const float4*)(s + 4);
        f16x8 H;
        H[0] = (f16)a.x; H[1] = (f16)a.y; H[2] = (f16)a.z; H[3] = (f16)a.w;
        H[4] = (f16)b.x; H[5] = (f16)b.y; H[6] = (f16)b.z; H[7] = (f16)b.w;
        *(f16x8*)&HV[((row >> 4) * 12 + (seg >> 2)) * 512 + (seg & 3) * 128 + (row & 15) * 8] = H;
    }
    // ---- init h_e (32*16 = 512 chunks)
    {
        const int row = tid / 16, seg = tid % 16;
        f16x8 H;
        #pragma unroll
        for (int j = 0; j < 8; ++j) H[j] = (f16)(eiw[seg * 8 + j] + eib[seg * 8 + j]);
        *(f16x8*)&HE[((row >> 4) * 4 + (seg >> 2)) * 512 + (seg & 3) * 128 + (row & 15) * 8] = H;
    }

    // ---- per-lane constants
    const int isByte = *flagp;
    unsigned mbits0 = 0, mbits1 = 0, mbits2 = 0;
    #pragma unroll
    for (int p = 0; p < 3; ++p) {
        unsigned mb = 0;
        #pragma unroll
        for (int mt = 0; mt < 2; ++mt)
            #pragma unroll
            for (int r = 0; r < 4; ++r) {
                const int v = (e0 + mt * 16 + lk * 4 + r) * 3 + p;
                const bool m = isByte ? (((const unsigned char*)mask)[v] != 0)
                                      : (((const int*)mask)[v] != 0);
                mb |= (unsigned)m << (mt * 4 + r);
            }
        if (p == 0) mbits0 = mb; else if (p == 1) mbits1 = mb; else mbits2 = mb;
    }
    const int d = c * 16 + lr;
    const int wBase = (c >> 1) * 512 + ((c & 1) * 2 + (lr >> 3)) * 128 + lk * 32 + (lr & 7);

    // cell state ALL in registers
    f32x4 ce0 = (f32x4)0.0f, ce1 = (f32x4)0.0f;      // c_e  (mt 0/1)
    f32x4 cv0a = (f32x4)0.0f, cv0b = (f32x4)0.0f;    // c_v p=0 (mt 0/1)
    f32x4 cv1a = (f32x4)0.0f, cv1b = (f32x4)0.0f;    // c_v p=1
    f32x4 cv2a = (f32x4)0.0f, cv2b = (f32x4)0.0f;    // c_v p=2

    __syncthreads();
    {
        int keep = (int)PADL[(tid + 1) & 511];
        asm volatile("" :: "v"(keep));
    }

    const f16* HVl = HV + l * 8;
    const f16* HEl = HE + l * 8;
    // per-wave weight bases (l*8 folded in)
    const f16* WvB = WvF + (size_t)c * 16 * 512 + l * 8;                  // + g*65536 + kk*512
    const f16* WeB = WeF + (size_t)c * 8 * 512 + l * 8;                   // + p*131072 + g*32768 + kk*512

    #pragma unroll 1
    for (int it = 0; it < ITERS_; ++it) {
        // ======== vertex -> edge ========
        {
            f32x4 acc[2][4];
            #pragma unroll
            for (int g = 0; g < 4; ++g) {
                const float bg = bv[g * 128 + d];
                acc[0][g] = (f32x4)bg; acc[1][g] = (f32x4)bg;
            }
            #pragma unroll
            for (int kk = 0; kk < 16; ++kk) {
                f16x8 A0, A1;
                if (kk < 12) {
                    A0 = *(const f16x8*)(HVl + kk * 512);
                    A1 = *(const f16x8*)(HVl + (12 + kk) * 512);
                } else {
                    A0 = *(const f16x8*)(HEl + (kk - 12) * 512);
                    A1 = *(const f16x8*)(HEl + (4 + kk - 12) * 512);
                }
                #pragma unroll
                for (int g = 0; g < 4; ++g) {
                    f16x8 B = *(const f16x8*)(WvB + (size_t)g * 65536 + kk * 512);
                    acc[0][g] = MFh(A0, B, acc[0][g]);
                    acc[1][g] = MFh(A1, B, acc[1][g]);
                }
            }
            __syncthreads();   // B1: WAR - all HE reads done before HE writes
            #pragma unroll
            for (int mt = 0; mt < 2; ++mt) {
                f32x4& ce = mt ? ce1 : ce0;
                #pragma unroll
                for (int r = 0; r < 4; ++r) {
                    float gi = sigmoid_f(acc[mt][0][r]);
                    float gf = sigmoid_f(acc[mt][1][r]);
                    float gg = tanh_f(acc[mt][2][r]);
                    float go = sigmoid_f(acc[mt][3][r]);
                    float cn = gf * ce[r] + gi * gg;
                    ce[r] = cn;
                    HE[wBase + mt * 2048 + r * 8] = (f16)(go * tanh_f(cn));
                }
            }
            __syncthreads();   // B2: RAW - HE ready for e2v
        }

        // ======== edge -> vertex: 3 pure-read GEMMs, cells hold h in regs ========
        u32 hh[3][4];   // packed h: [p][mt*2 + rpair] - ALL indices compile-time

#define E2V_PHASE(P, MB, CVA, CVB)                                              \
        {                                                                       \
            f32x4 acc[2][4];                                                    \
            _Pragma("unroll")                                                   \
            for (int g = 0; g < 4; ++g) {                                       \
                const float bg = be[(P) * 512 + g * 128 + d];                   \
                acc[0][g] = (f32x4)bg; acc[1][g] = (f32x4)bg;                   \
            }                                                                   \
            _Pragma("unroll")                                                   \
            for (int kk = 0; kk < 8; ++kk) {                                    \
                f16x8 A0, A1;                                                   \
                if (kk < 4) {                                                   \
                    A0 = *(const f16x8*)(HEl + kk * 512);                       \
                    A1 = *(const f16x8*)(HEl + (4 + kk) * 512);                 \
                } else {                                                        \
                    A0 = *(const f16x8*)(HVl + ((P) * 4 + kk - 4) * 512);       \
                    A1 = *(const f16x8*)(HVl + (12 + (P) * 4 + kk - 4) * 512);  \
                }                                                               \
                _Pragma("unroll")                                               \
                for (int g = 0; g < 4; ++g) {                                   \
                    f16x8 B = *(const f16x8*)(WeB + (size_t)(P) * 131072        \
                                              + (size_t)g * 32768 + kk * 512);  \
                    acc[0][g] = MFh(A0, B, acc[0][g]);                          \
                    acc[1][g] = MFh(A1, B, acc[1][g]);                          \
                }                                                               \
            }                                                                   \
            _Pragma("unroll")                                                   \
            for (int mt = 0; mt < 2; ++mt) {                                    \
                f32x4& cv = mt ? (CVB) : (CVA);                                 \
                u16 hb[4];                                                      \
                _Pragma("unroll")                                               \
                for (int r = 0; r < 4; ++r) {                                   \
                    float gi = sigmoid_f(acc[mt][0][r]);                        \
                    float gf = sigmoid_f(acc[mt][1][r]);                        \
                    float gg = tanh_f(acc[mt][2][r]);                           \
                    float go = sigmoid_f(acc[mt][3][r]);                        \
                    float cn = gf * cv[r] + gi * gg;                            \
                    if (((MB) >> (mt * 4 + r)) & 1u) cv[r] = cn;                \
                    hb[r] = f16bits((f16)(go * tanh_f(cn)));                    \
                }                                                               \
                hh[P][mt * 2]     = (u32)hb[0] | ((u32)hb[1] << 16);            \
                hh[P][mt * 2 + 1] = (u32)hb[2] | ((u32)hb[3] << 16);            \
            }                                                                   \
        }

        E2V_PHASE(0, mbits0, cv0a, cv0b)
        E2V_PHASE(1, mbits1, cv1a, cv1b)
        E2V_PHASE(2, mbits2, cv2a, cv2b)
#undef E2V_PHASE

        __syncthreads();   // B3: WAR - all e2v HV reads complete

        #pragma unroll
        for (int p = 0; p < 3; ++p) {
            const unsigned mb = (p == 0) ? mbits0 : ((p == 1) ? mbits1 : mbits2);
            #pragma unroll
            for (int mt = 0; mt < 2; ++mt)
                #pragma unroll
                for (int r = 0; r < 4; ++r)
                    if ((mb >> (mt * 4 + r)) & 1u) {
                        u32 w = hh[p][mt * 2 + (r >> 1)];
                        u16 hb = (r & 1) ? (u16)(w >> 16) : (u16)(w & 0xFFFF);
                        HV[wBase + mt * 6144 + p * 2048 + r * 8] = bits2f16(hb);
                    }
        }
        __syncthreads();   // B4: iter end
    }

    // ---- write final h_v (fp16): [vertex][128] row-major
    for (int i = tid; i < 32 * 48; i += 512) {
        const int row = i / 48, seg = i % 48;
        *(f16x8*)&hvOut[(size_t)(e0 + row) * 384 + seg * 8] =
            *(const f16x8*)&HV[((row >> 4) * 12 + (seg >> 2)) * 512 + (seg & 3) * 128 + (row & 15) * 8];
    }
}

// logits = h_v @ out_w^T + out_b, swapped MFMA operands (A=out_w, B=h_v) -> each lane
// holds 4 consecutive vocab cols for one vertex -> float4 stores.
// Single fp16 W term. 768 blocks x 256 thr -> full coverage. W register dbuf.
__global__ __launch_bounds__(256) void proj_kernel(
    const f16* __restrict__ hv, const f16* __restrict__ WF,
    const float* __restrict__ out_b, float* __restrict__ out)
{
    __shared__ char occ_pad[49152];
    const int tid = threadIdx.x, l = tid & 63;
    occ_pad[tid] = (char)tid;
    __syncthreads();
    {
        int keep = (int)occ_pad[(tid + 1) & 255];
        asm volatile("" :: "v"(keep));
    }

    const int wid = blockIdx.x * 4 + (tid >> 6);   // 0..3071
    const int v0 = wid * 32;
    const int lr = l & 15, lk = l >> 4;

    f16x8 Bv[2][4];
    #pragma unroll
    for (int vt = 0; vt < 2; ++vt)
        #pragma unroll
        for (int kk = 0; kk < 4; ++kk)
            Bv[vt][kk] = *(const f16x8*)(hv + (v0 + vt * 16 + lr) * D_ + kk * 32 + lk * 8);

    f16x8 Wc[4];
    #pragma unroll
    for (int kk = 0; kk < 4; ++kk)
        Wc[kk] = *(const f16x8*)(WF + (kk * 64 + l) * 8);

    #pragma unroll 2
    for (int nt = 0; nt < 125; ++nt) {
        f16x8 Wn[4];
        if (nt < 124) {
            #pragma unroll
            for (int kk = 0; kk < 4; ++kk)
                Wn[kk] = *(const f16x8*)(WF + (((nt + 1) * 4 + kk) * 64 + l) * 8);
        }
        f32x4 a0 = (f32x4)0.0f, a1 = (f32x4)0.0f;
        #pragma unroll
        for (int kk = 0; kk < 4; ++kk) {
            a0 = MFh(Wc[kk], Bv[0][kk], a0);
            a1 = MFh(Wc[kk], Bv[1][kk], a1);
        }
        const int n0 = nt * 16 + lk * 4;
        const float4 bb = *(const float4*)&out_b[n0];
        {
            const size_t v = (size_t)(v0 + lr);
            float4 o = make_float4(a0[0] + bb.x, a0[1] + bb.y, a0[2] + bb.z, a0[3] + bb.w);
            *(float4*)&out[v * VOCAB_ + n0] = o;
        }
        {
            const size_t v = (size_t)(v0 + 16 + lr);
            float4 o = make_float4(a1[0] + bb.x, a1[1] + bb.y, a1[2] + bb.z, a1[3] + bb.w);
            *(float4*)&out[v * VOCAB_ + n0] = o;
        }
        #pragma unroll
        for (int q = 0; q < 4; ++q) Wc[q] = Wn[q];
    }
}

extern "C" void kernel_launch(void* const* d_in, const int* in_sizes, int n_in,
                              void* d_out, int out_size, void* d_ws, size_t ws_size,
                              hipStream_t stream)
{
    const int*   x_v     = (const int*)  d_in[0];
    const void*  mask    = d_in[1];
    const float* emb     = (const float*)d_in[2];
    const float* eiw     = (const float*)d_in[3];
    const float* eib     = (const float*)d_in[4];
    const float* Wih_v2e = (const float*)d_in[5];
    const float* Whh_v2e = (const float*)d_in[6];
    const float* bih_v2e = (const float*)d_in[7];
    const float* bhh_v2e = (const float*)d_in[8];
    const float* Wih_e2v = (const float*)d_in[9];
    const float* Whh_e2v = (const float*)d_in[10];
    const float* bih_e2v = (const float*)d_in[11];
    const float* bhh_e2v = (const float*)d_in[12];
    const float* out_w   = (const float*)d_in[13];
    const float* out_b   = (const float*)d_in[14];
    float* out = (float*)d_out;

    // d_ws carve (~27 MB)
    char* ws = (char*)d_ws;
    f16*    hv   = (f16*)(ws);                  // 25165824 B
    f16*    WvF  = (f16*)(ws + 25165824);       // 524288
    f16*    WeF  = (f16*)(ws + 25690112);       // 786432
    f16*    OwF  = (f16*)(ws + 26476544);       // 512000
    float*  bv   = (float*)(ws + 26988544);     // 2048
    float*  be   = (float*)(ws + 26990592);     // 6144
    int*    flag = (int*)(ws + 26996736);       // 4

    hipMemsetAsync(flag, 0, 4, stream);
    detect_mask_kernel<<<16, 256, 0, stream>>>((const unsigned int*)mask, flag);
    prep_kernel<<<3568, 256, 0, stream>>>(Wih_v2e, Whh_v2e, bih_v2e, bhh_v2e,
                                          Wih_e2v, Whh_e2v, bih_e2v, bhh_e2v, out_w,
                                          WvF, WeF, OwF, bv, be);
    fused_kernel<<<E_CNT / 32, 512, 0, stream>>>(x_v, emb, eiw, eib,
                                                 WvF, WeF, bv, be,
                                                 mask, flag, hv);
    proj_kernel<<<V_CNT / 128, 256, 0, stream>>>(hv, OwF, out_b, out);
}

// Round 21
// 2510.079 us; speedup vs baseline: 1.0607x; 1.0607x over previous
//
#include <hip/hip_runtime.h>

#define E_CNT 32768
#define V_CNT 98304
#define D_ 128
#define VOCAB_ 2000
#define ITERS_ 6

typedef unsigned short u16;
typedef _Float16 f16;
typedef __attribute__((ext_vector_type(8))) _Float16 f16x8;
typedef __attribute__((ext_vector_type(4))) float f32x4;

__device__ __forceinline__ f32x4 MFh(f16x8 a, f16x8 b, f32x4 c) {
    return __builtin_amdgcn_mfma_f32_16x16x32_f16(a, b, c, 0, 0, 0);
}
__device__ __forceinline__ float sigmoid_f(float x) {
    return __builtin_amdgcn_rcpf(1.0f + __expf(-x));
}
__device__ __forceinline__ float tanh_f(float x) {
    return fmaf(2.0f, __builtin_amdgcn_rcpf(1.0f + __expf(-2.0f * x)), -1.0f);
}

__global__ void detect_mask_kernel(const unsigned int* __restrict__ m, int* __restrict__ flag) {
    int i = blockIdx.x * 256 + threadIdx.x;
    if (i < 4096 && m[i] > 1u) atomicOr(flag, 1);
}

// Pack weights into MFMA fragment order.
// WvF (fp16): [nt(32)][kk(16)][lane(64)][8]  j = nt*16+(l&15), k = kk*32+(l>>4)*8+r
// WeF (fp16): [p(3)][nt(32)][kk(8)][64][8]
// OwF (fp16, single term): [nt(125)][kk(4)][64][8]
__global__ void prep_kernel(
    const float* __restrict__ Wih_v2e, const float* __restrict__ Whh_v2e,
    const float* __restrict__ bih_v2e, const float* __restrict__ bhh_v2e,
    const float* __restrict__ Wih_e2v, const float* __restrict__ Whh_e2v,
    const float* __restrict__ bih_e2v, const float* __restrict__ bhh_e2v,
    const float* __restrict__ out_w,
    f16* __restrict__ WvF, f16* __restrict__ WeF, f16* __restrict__ OwF,
    float* __restrict__ bv, float* __restrict__ be)
{
    int idx = blockIdx.x * 256 + threadIdx.x;
    if (idx < 262144) {
        const int r = idx & 7, l = (idx >> 3) & 63, t = idx >> 9;
        const int kk = t & 15, nt = t >> 4;
        const int j = nt * 16 + (l & 15);
        const int k = kk * 32 + (l >> 4) * 8 + r;
        const float w = (k < 384) ? Wih_v2e[j * 384 + k] : Whh_v2e[j * 128 + (k - 384)];
        WvF[idx] = (f16)w;
        return;
    }
    idx -= 262144;
    if (idx < 393216) {
        const int r = idx & 7, l = (idx >> 3) & 63, t = idx >> 9;  // t < 768
        const int kk = t & 7, nt = (t >> 3) & 31, p = t >> 8;
        const int j = nt * 16 + (l & 15);
        const int k = kk * 32 + (l >> 4) * 8 + r;
        const float w = (k < 128) ? Wih_e2v[(p * 512 + j) * 128 + k]
                                  : Whh_e2v[(p * 512 + j) * 128 + (k - 128)];
        WeF[idx] = (f16)w;
        return;
    }
    idx -= 393216;
    if (idx < 256000) {
        const int r = idx & 7, l = (idx >> 3) & 63, t = idx >> 9;  // t < 500
        const int kk = t & 3, nt = t >> 2;
        const int j = nt * 16 + (l & 15);
        const int k = kk * 32 + (l >> 4) * 8 + r;
        OwF[idx] = (f16)out_w[j * 128 + k];
        return;
    }
    idx -= 256000;
    if (idx < 512) { bv[idx] = bih_v2e[idx] + bhh_v2e[idx]; return; }
    idx -= 512;
    if (idx < 1536) { be[idx] = bih_e2v[idx] + bhh_e2v[idx]; return; }
}

// Persistent iteration kernel: 512 thr / 8 waves / 32 edges / all 6 iterations.
// r21 = r19 (best: 475us fused, VGPR 48, no spills) + EXPANDED PHASES ONLY:
// the unified phase loop's runtime selects (nkk/sa/sb/ob multiplies per kk) were
// 48% VALUBusy; explicit v2e + three constant-P e2v macros make every LDS/weight
// offset a compile-time immediate. c_v stays in coalesced GLOBAL float4 (r20's
// register-resident c_v spilled 5.9 GB - reverted). ce stays in regs.
// LDS 41.4 KB (24K HV + 8K HE + 8.5K pad): 3 blocks/CU max -> 85-VGPR budget >=
// live ~75. 6 barriers/iter (per-phase WAR + 2 RAW).
__global__ __launch_bounds__(512)
void fused_kernel(
    const int* __restrict__ x_v,
    const float* __restrict__ emb,
    const float* __restrict__ eiw, const float* __restrict__ eib,
    const f16* __restrict__ WvF, const f16* __restrict__ WeF,
    const float* __restrict__ bv, const float* __restrict__ be,
    const void* __restrict__ mask, const int* __restrict__ flagp,
    float4* __restrict__ cvG4,
    f16* __restrict__ hvOut)
{
    __shared__ f16 HV[12288];    // 24 KB [mt(2)*12+kk][lane][8]
    __shared__ f16 HE[4096];     //  8 KB [mt(2)*4+kk][lane][8]
    __shared__ char PADL[8704];  //  8.5 KB occupancy governor -> 3 blocks/CU max

    const int tid = threadIdx.x;
    const int c = tid >> 6, l = tid & 63;
    const int lr = l & 15, lk = l >> 4;
    const int e0 = blockIdx.x * 32;

    PADL[tid] = (char)tid;

    // ---- init h_v from embeddings
    for (int i = tid; i < 32 * 48; i += 512) {
        const int row = i / 48, seg = i % 48;
        int id = x_v[(e0 + row) * 3 + (seg >> 4)];
        if (id < 0 || id > VOCAB_) id = VOCAB_;
        const float* s = emb + id * D_ + ((seg * 8) & 127);
        float4 a = *(const float4*)s, b = *(const float4*)(s + 4);
        f16x8 H;
        H[0] = (f16)a.x; H[1] = (f16)a.y; H[2] = (f16)a.z; H[3] = (f16)a.w;
        H[4] = (f16)b.x; H[5] = (f16)b.y; H[6] = (f16)b.z; H[7] = (f16)b.w;
        *(f16x8*)&HV[((row >> 4) * 12 + (seg >> 2)) * 512 + (seg & 3) * 128 + (row & 15) * 8] = H;
    }
    // ---- init h_e (32*16 = 512 chunks)
    {
        const int row = tid / 16, seg = tid % 16;
        f16x8 H;
        #pragma unroll
        for (int j = 0; j < 8; ++j) H[j] = (f16)(eiw[seg * 8 + j] + eib[seg * 8 + j]);
        *(f16x8*)&HE[((row >> 4) * 4 + (seg >> 2)) * 512 + (seg & 3) * 128 + (row & 15) * 8] = H;
    }

    // ---- per-lane constants
    const int isByte = *flagp;
    unsigned mbits0 = 0, mbits1 = 0, mbits2 = 0;
    #pragma unroll
    for (int p = 0; p < 3; ++p) {
        unsigned mb = 0;
        #pragma unroll
        for (int mt = 0; mt < 2; ++mt)
            #pragma unroll
            for (int r = 0; r < 4; ++r) {
                const int v = (e0 + mt * 16 + lk * 4 + r) * 3 + p;
                const bool m = isByte ? (((const unsigned char*)mask)[v] != 0)
                                      : (((const int*)mask)[v] != 0);
                mb |= (unsigned)m << (mt * 4 + r);
            }
        if (p == 0) mbits0 = mb; else if (p == 1) mbits1 = mb; else mbits2 = mb;
    }
    const int d = c * 16 + lr;
    const int wBase = (c >> 1) * 512 + ((c & 1) * 2 + (lr >> 3)) * 128 + lk * 32 + (lr & 7);
    f32x4 ce0 = (f32x4)0.0f, ce1 = (f32x4)0.0f;

    __syncthreads();
    {
        int keep = (int)PADL[(tid + 1) & 511];
        asm volatile("" :: "v"(keep));
    }

    const f16* HVl = HV + l * 8;
    const f16* HEl = HE + l * 8;
    const f16* WvB = WvF + (size_t)c * 16 * 512 + l * 8;   // + g*65536 + kk*512
    const f16* WeB = WeF + (size_t)c * 8 * 512 + l * 8;    // + P*131072 + g*32768 + kk*512
    const size_t cvBase = (size_t)blockIdx.x * 6 * 512 + tid;   // float4 units

    #pragma unroll 1
    for (int it = 0; it < ITERS_; ++it) {
        // ======== vertex -> edge (all offsets compile-time) ========
        {
            f32x4 acc[2][4];
            #pragma unroll
            for (int g = 0; g < 4; ++g) {
                const float bg = bv[g * 128 + d];
                acc[0][g] = (f32x4)bg; acc[1][g] = (f32x4)bg;
            }
            #pragma unroll
            for (int kk = 0; kk < 16; ++kk) {
                f16x8 A0, A1;
                if (kk < 12) {
                    A0 = *(const f16x8*)(HVl + kk * 512);
                    A1 = *(const f16x8*)(HVl + (12 + kk) * 512);
                } else {
                    A0 = *(const f16x8*)(HEl + (kk - 12) * 512);
                    A1 = *(const f16x8*)(HEl + (4 + kk - 12) * 512);
                }
                #pragma unroll
                for (int g = 0; g < 4; ++g) {
                    f16x8 B = *(const f16x8*)(WvB + (size_t)g * 65536 + kk * 512);
                    acc[0][g] = MFh(A0, B, acc[0][g]);
                    acc[1][g] = MFh(A1, B, acc[1][g]);
                }
            }
            __syncthreads();   // WAR: all HE reads done before HE writes
            #pragma unroll
            for (int mt = 0; mt < 2; ++mt) {
                f32x4& ce = mt ? ce1 : ce0;
                #pragma unroll
                for (int r = 0; r < 4; ++r) {
                    float gi = sigmoid_f(acc[mt][0][r]);
                    float gf = sigmoid_f(acc[mt][1][r]);
                    float gg = tanh_f(acc[mt][2][r]);
                    float go = sigmoid_f(acc[mt][3][r]);
                    float cn = gf * ce[r] + gi * gg;
                    ce[r] = cn;
                    HE[wBase + mt * 2048 + r * 8] = (f16)(go * tanh_f(cn));
                }
            }
            __syncthreads();   // RAW: HE ready for e2v
        }

        // ======== edge -> vertex: three expanded phases, constant offsets ========
        // Per phase: GEMM (pure reads) -> WAR barrier -> cell writes HV p-tiles +
        // cvG4. No barrier between cell(P) and GEMM(P+1): disjoint LDS tiles.
#define E2V_PHASE(P, MB)                                                        \
        {                                                                       \
            f32x4 acc[2][4];                                                    \
            _Pragma("unroll")                                                   \
            for (int g = 0; g < 4; ++g) {                                       \
                const float bg = be[(P) * 512 + g * 128 + d];                   \
                acc[0][g] = (f32x4)bg; acc[1][g] = (f32x4)bg;                   \
            }                                                                   \
            _Pragma("unroll")                                                   \
            for (int kk = 0; kk < 8; ++kk) {                                    \
                f16x8 A0, A1;                                                   \
                if (kk < 4) {                                                   \
                    A0 = *(const f16x8*)(HEl + kk * 512);                       \
                    A1 = *(const f16x8*)(HEl + (4 + kk) * 512);                 \
                } else {                                                        \
                    A0 = *(const f16x8*)(HVl + ((P) * 4 + kk - 4) * 512);       \
                    A1 = *(const f16x8*)(HVl + (12 + (P) * 4 + kk - 4) * 512);  \
                }                                                               \
                _Pragma("unroll")                                               \
                for (int g = 0; g < 4; ++g) {                                   \
                    f16x8 B = *(const f16x8*)(WeB + (size_t)(P) * 131072        \
                                              + (size_t)g * 32768 + kk * 512);  \
                    acc[0][g] = MFh(A0, B, acc[0][g]);                          \
                    acc[1][g] = MFh(A1, B, acc[1][g]);                          \
                }                                                               \
            }                                                                   \
            __syncthreads();  /* WAR: HV[P]/HE reads done before HV[P] writes */\
            _Pragma("unroll")                                                   \
            for (int mt = 0; mt < 2; ++mt) {                                    \
                const size_t ci = cvBase + (size_t)((P) * 2 + mt) * 512;        \
                float cvv[4];                                                   \
                if (it > 0) {                                                   \
                    float4 t = cvG4[ci];                                        \
                    cvv[0] = t.x; cvv[1] = t.y; cvv[2] = t.z; cvv[3] = t.w;     \
                } else {                                                        \
                    cvv[0] = cvv[1] = cvv[2] = cvv[3] = 0.0f;                   \
                }                                                               \
                _Pragma("unroll")                                               \
                for (int r = 0; r < 4; ++r) {                                   \
                    if (((MB) >> (mt * 4 + r)) & 1u) {                          \
                        float gi = sigmoid_f(acc[mt][0][r]);                    \
                        float gf = sigmoid_f(acc[mt][1][r]);                    \
                        float gg = tanh_f(acc[mt][2][r]);                       \
                        float go = sigmoid_f(acc[mt][3][r]);                    \
                        float cn = gf * cvv[r] + gi * gg;                       \
                        cvv[r] = cn;                                            \
                        HV[wBase + mt * 6144 + (P) * 2048 + r * 8] =            \
                            (f16)(go * tanh_f(cn));                             \
                    }                                                           \
                }                                                               \
                cvG4[ci] = make_float4(cvv[0], cvv[1], cvv[2], cvv[3]);         \
            }                                                                   \
        }

        E2V_PHASE(0, mbits0)
        E2V_PHASE(1, mbits1)
        E2V_PHASE(2, mbits2)
#undef E2V_PHASE

        __syncthreads();   // iter end: HV writes complete before next v2e
    }

    // ---- write final h_v (fp16): [vertex][128] row-major
    for (int i = tid; i < 32 * 48; i += 512) {
        const int row = i / 48, seg = i % 48;
        *(f16x8*)&hvOut[(size_t)(e0 + row) * 384 + seg * 8] =
            *(const f16x8*)&HV[((row >> 4) * 12 + (seg >> 2)) * 512 + (seg & 3) * 128 + (row & 15) * 8];
    }
}

// logits = h_v @ out_w^T + out_b, swapped MFMA operands (A=out_w, B=h_v) -> each lane
// holds 4 consecutive vocab cols for one vertex -> float4 stores.
// Single fp16 W term. 768 blocks x 256 thr -> full coverage. W register dbuf.
__global__ __launch_bounds__(256) void proj_kernel(
    const f16* __restrict__ hv, const f16* __restrict__ WF,
    const float* __restrict__ out_b, float* __restrict__ out)
{
    __shared__ char occ_pad[49152];
    const int tid = threadIdx.x, l = tid & 63;
    occ_pad[tid] = (char)tid;
    __syncthreads();
    {
        int keep = (int)occ_pad[(tid + 1) & 255];
        asm volatile("" :: "v"(keep));
    }

    const int wid = blockIdx.x * 4 + (tid >> 6);   // 0..3071
    const int v0 = wid * 32;
    const int lr = l & 15, lk = l >> 4;

    f16x8 Bv[2][4];
    #pragma unroll
    for (int vt = 0; vt < 2; ++vt)
        #pragma unroll
        for (int kk = 0; kk < 4; ++kk)
            Bv[vt][kk] = *(const f16x8*)(hv + (v0 + vt * 16 + lr) * D_ + kk * 32 + lk * 8);

    f16x8 Wc[4];
    #pragma unroll
    for (int kk = 0; kk < 4; ++kk)
        Wc[kk] = *(const f16x8*)(WF + (kk * 64 + l) * 8);

    #pragma unroll 2
    for (int nt = 0; nt < 125; ++nt) {
        f16x8 Wn[4];
        if (nt < 124) {
            #pragma unroll
            for (int kk = 0; kk < 4; ++kk)
                Wn[kk] = *(const f16x8*)(WF + (((nt + 1) * 4 + kk) * 64 + l) * 8);
        }
        f32x4 a0 = (f32x4)0.0f, a1 = (f32x4)0.0f;
        #pragma unroll
        for (int kk = 0; kk < 4; ++kk) {
            a0 = MFh(Wc[kk], Bv[0][kk], a0);
            a1 = MFh(Wc[kk], Bv[1][kk], a1);
        }
        const int n0 = nt * 16 + lk * 4;
        const float4 bb = *(const float4*)&out_b[n0];
        {
            const size_t v = (size_t)(v0 + lr);
            float4 o = make_float4(a0[0] + bb.x, a0[1] + bb.y, a0[2] + bb.z, a0[3] + bb.w);
            *(float4*)&out[v * VOCAB_ + n0] = o;
        }
        {
            const size_t v = (size_t)(v0 + 16 + lr);
            float4 o = make_float4(a1[0] + bb.x, a1[1] + bb.y, a1[2] + bb.z, a1[3] + bb.w);
            *(float4*)&out[v * VOCAB_ + n0] = o;
        }
        #pragma unroll
        for (int q = 0; q < 4; ++q) Wc[q] = Wn[q];
    }
}

extern "C" void kernel_launch(void* const* d_in, const int* in_sizes, int n_in,
                              void* d_out, int out_size, void* d_ws, size_t ws_size,
                              hipStream_t stream)
{
    const int*   x_v     = (const int*)  d_in[0];
    const void*  mask    = d_in[1];
    const float* emb     = (const float*)d_in[2];
    const float* eiw     = (const float*)d_in[3];
    const float* eib     = (const float*)d_in[4];
    const float* Wih_v2e = (const float*)d_in[5];
    const float* Whh_v2e = (const float*)d_in[6];
    const float* bih_v2e = (const float*)d_in[7];
    const float* bhh_v2e = (const float*)d_in[8];
    const float* Wih_e2v = (const float*)d_in[9];
    const float* Whh_e2v = (const float*)d_in[10];
    const float* bih_e2v = (const float*)d_in[11];
    const float* bhh_e2v = (const float*)d_in[12];
    const float* out_w   = (const float*)d_in[13];
    const float* out_b   = (const float*)d_in[14];
    float* out = (float*)d_out;

    // d_ws carve (~77.3 MB)
    char* ws = (char*)d_ws;
    f16*    hv   = (f16*)(ws);                  // 25165824 B
    f16*    WvF  = (f16*)(ws + 25165824);       // 524288
    f16*    WeF  = (f16*)(ws + 25690112);       // 786432
    f16*    OwF  = (f16*)(ws + 26476544);       // 512000
    float*  bv   = (float*)(ws + 26988544);     // 2048
    float*  be   = (float*)(ws + 26990592);     // 6144
    int*    flag = (int*)(ws + 26996736);       // 4
    float4* cvG4 = (float4*)(ws + 27000832);    // 50331648  [blk][(p*2+mt)][tid] float4

    hipMemsetAsync(flag, 0, 4, stream);
    detect_mask_kernel<<<16, 256, 0, stream>>>((const unsigned int*)mask, flag);
    prep_kernel<<<3568, 256, 0, stream>>>(Wih_v2e, Whh_v2e, bih_v2e, bhh_v2e,
                                          Wih_e2v, Whh_e2v, bih_e2v, bhh_e2v, out_w,
                                          WvF, WeF, OwF, bv, be);
    fused_kernel<<<E_CNT / 32, 512, 0, stream>>>(x_v, emb, eiw, eib,
                                                 WvF, WeF, bv, be,
                                                 mask, flag, cvG4, hv);
    proj_kernel<<<V_CNT / 128, 256, 0, stream>>>(hv, OwF, out_b, out);
}

// Round 22
// 790.491 us; speedup vs baseline: 3.3682x; 3.1753x over previous
//
#include <hip/hip_runtime.h>

#define E_CNT 32768
#define V_CNT 98304
#define D_ 128
#define VOCAB_ 2000
#define ITERS_ 6

typedef unsigned short u16;
typedef _Float16 f16;
typedef __attribute__((ext_vector_type(8))) _Float16 f16x8;
typedef __attribute__((ext_vector_type(4))) float f32x4;

__device__ __forceinline__ f32x4 MFh(f16x8 a, f16x8 b, f32x4 c) {
    return __builtin_amdgcn_mfma_f32_16x16x32_f16(a, b, c, 0, 0, 0);
}
__device__ __forceinline__ float sigmoid_f(float x) {
    return __builtin_amdgcn_rcpf(1.0f + __expf(-x));
}
__device__ __forceinline__ float tanh_f(float x) {
    return fmaf(2.0f, __builtin_amdgcn_rcpf(1.0f + __expf(-2.0f * x)), -1.0f);
}

__global__ void detect_mask_kernel(const unsigned int* __restrict__ m, int* __restrict__ flag) {
    int i = blockIdx.x * 256 + threadIdx.x;
    if (i < 4096 && m[i] > 1u) atomicOr(flag, 1);
}

// Pack weights into MFMA fragment order.
// WvF (fp16): [nt(32)][kk(16)][lane(64)][8]  j = nt*16+(l&15), k = kk*32+(l>>4)*8+r
// WeF (fp16): [p(3)][nt(32)][kk(8)][64][8]
// OwF (fp16, single term): [nt(125)][kk(4)][64][8]
__global__ void prep_kernel(
    const float* __restrict__ Wih_v2e, const float* __restrict__ Whh_v2e,
    const float* __restrict__ bih_v2e, const float* __restrict__ bhh_v2e,
    const float* __restrict__ Wih_e2v, const float* __restrict__ Whh_e2v,
    const float* __restrict__ bih_e2v, const float* __restrict__ bhh_e2v,
    const float* __restrict__ out_w,
    f16* __restrict__ WvF, f16* __restrict__ WeF, f16* __restrict__ OwF,
    float* __restrict__ bv, float* __restrict__ be)
{
    int idx = blockIdx.x * 256 + threadIdx.x;
    if (idx < 262144) {
        const int r = idx & 7, l = (idx >> 3) & 63, t = idx >> 9;
        const int kk = t & 15, nt = t >> 4;
        const int j = nt * 16 + (l & 15);
        const int k = kk * 32 + (l >> 4) * 8 + r;
        const float w = (k < 384) ? Wih_v2e[j * 384 + k] : Whh_v2e[j * 128 + (k - 384)];
        WvF[idx] = (f16)w;
        return;
    }
    idx -= 262144;
    if (idx < 393216) {
        const int r = idx & 7, l = (idx >> 3) & 63, t = idx >> 9;  // t < 768
        const int kk = t & 7, nt = (t >> 3) & 31, p = t >> 8;
        const int j = nt * 16 + (l & 15);
        const int k = kk * 32 + (l >> 4) * 8 + r;
        const float w = (k < 128) ? Wih_e2v[(p * 512 + j) * 128 + k]
                                  : Whh_e2v[(p * 512 + j) * 128 + (k - 128)];
        WeF[idx] = (f16)w;
        return;
    }
    idx -= 393216;
    if (idx < 256000) {
        const int r = idx & 7, l = (idx >> 3) & 63, t = idx >> 9;  // t < 500
        const int kk = t & 3, nt = t >> 2;
        const int j = nt * 16 + (l & 15);
        const int k = kk * 32 + (l >> 4) * 8 + r;
        OwF[idx] = (f16)out_w[j * 128 + k];
        return;
    }
    idx -= 256000;
    if (idx < 512) { bv[idx] = bih_v2e[idx] + bhh_v2e[idx]; return; }
    idx -= 512;
    if (idx < 1536) { be[idx] = bih_e2v[idx] + bhh_e2v[idx]; return; }
}

// Persistent iteration kernel: 512 thr / 8 waves / 32 edges / all 6 iterations.
// r22 = r19 (best: 475us fused, VGPR 48, no spills) with ONE micro change: the
// unified kk-loop is split into two sequential sub-loops (pa then pb), removing the
// per-kk `lo ?:` selects. Phase-level selects stay wave-uniform SGPRs (cheap, as in
// r19). UNIFIED COMPACT LOOP IS MANDATORY: both expansions (r20 regs, r21 phases)
// ballooned live ranges -> VGPR 128 + multi-GB scratch spills. Do not expand.
// LDS 41.4 KB (24K HV + 8K HE + 8.5K pad): 3 blocks/CU max -> 85-VGPR budget.
// c_v in coalesced global float4 (r15); ce in regs; 6 barriers/iter.
__global__ __launch_bounds__(512)
void fused_kernel(
    const int* __restrict__ x_v,
    const float* __restrict__ emb,
    const float* __restrict__ eiw, const float* __restrict__ eib,
    const f16* __restrict__ WvF, const f16* __restrict__ WeF,
    const float* __restrict__ bv, const float* __restrict__ be,
    const void* __restrict__ mask, const int* __restrict__ flagp,
    float4* __restrict__ cvG4,
    f16* __restrict__ hvOut)
{
    __shared__ f16 HV[12288];    // 24 KB [mt(2)*12+kk][lane][8]
    __shared__ f16 HE[4096];     //  8 KB [mt(2)*4+kk][lane][8]
    __shared__ char PADL[8704];  //  8.5 KB occupancy governor -> 3 blocks/CU max

    const int tid = threadIdx.x;
    const int c = tid >> 6, l = tid & 63;
    const int lr = l & 15, lk = l >> 4;
    const int e0 = blockIdx.x * 32;

    PADL[tid] = (char)tid;

    // ---- init h_v from embeddings
    for (int i = tid; i < 32 * 48; i += 512) {
        const int row = i / 48, seg = i % 48;
        int id = x_v[(e0 + row) * 3 + (seg >> 4)];
        if (id < 0 || id > VOCAB_) id = VOCAB_;
        const float* s = emb + id * D_ + ((seg * 8) & 127);
        float4 a = *(const float4*)s, b = *(const float4*)(s + 4);
        f16x8 H;
        H[0] = (f16)a.x; H[1] = (f16)a.y; H[2] = (f16)a.z; H[3] = (f16)a.w;
        H[4] = (f16)b.x; H[5] = (f16)b.y; H[6] = (f16)b.z; H[7] = (f16)b.w;
        *(f16x8*)&HV[((row >> 4) * 12 + (seg >> 2)) * 512 + (seg & 3) * 128 + (row & 15) * 8] = H;
    }
    // ---- init h_e (32*16 = 512 chunks)
    {
        const int row = tid / 16, seg = tid % 16;
        f16x8 H;
        #pragma unroll
        for (int j = 0; j < 8; ++j) H[j] = (f16)(eiw[seg * 8 + j] + eib[seg * 8 + j]);
        *(f16x8*)&HE[((row >> 4) * 4 + (seg >> 2)) * 512 + (seg & 3) * 128 + (row & 15) * 8] = H;
    }

    // ---- per-lane constants
    const int isByte = *flagp;
    unsigned mbits0 = 0, mbits1 = 0, mbits2 = 0;
    #pragma unroll
    for (int p = 0; p < 3; ++p) {
        unsigned mb = 0;
        #pragma unroll
        for (int mt = 0; mt < 2; ++mt)
            #pragma unroll
            for (int r = 0; r < 4; ++r) {
                const int v = (e0 + mt * 16 + lk * 4 + r) * 3 + p;
                const bool m = isByte ? (((const unsigned char*)mask)[v] != 0)
                                      : (((const int*)mask)[v] != 0);
                mb |= (unsigned)m << (mt * 4 + r);
            }
        if (p == 0) mbits0 = mb; else if (p == 1) mbits1 = mb; else mbits2 = mb;
    }
    const int d = c * 16 + lr;
    const int wBase = (c >> 1) * 512 + ((c & 1) * 2 + (lr >> 3)) * 128 + lk * 32 + (lr & 7);
    f32x4 ce[2];
    ce[0] = (f32x4)0.0f; ce[1] = (f32x4)0.0f;

    __syncthreads();
    {
        int keep = (int)PADL[(tid + 1) & 511];
        asm volatile("" :: "v"(keep));
    }

    const f16* HVl = HV + l * 8;
    const f16* HEl = HE + l * 8;
    const size_t cvBase = (size_t)blockIdx.x * 6 * 512 + tid;   // float4 units

    #pragma unroll 1
    for (int it = 0; it < ITERS_; ++it) {
        #pragma unroll 1
        for (int ph = 0; ph < 4; ++ph) {
            const int  nkk = (ph == 0) ? 16 : 8;
            const int  ksp = (ph == 0) ? 12 : 4;
            const f16* pa  = (ph == 0) ? HVl : HEl;
            const int  sa  = (ph == 0) ? 12 : 4;
            const f16* pb  = (ph == 0) ? HEl : HVl;
            const int  sb  = (ph == 0) ? 4 : 12;
            const int  ob  = (ph == 0) ? 0 : (ph - 1) * 4;
            const f16* Wp  = (ph == 0) ? WvF : (WeF + (size_t)(ph - 1) * 131072);
            const float* bp = (ph == 0) ? bv : (be + (ph - 1) * 512);
            const unsigned mb = (ph == 0) ? 0xFFu
                              : ((ph == 1) ? mbits0 : ((ph == 2) ? mbits1 : mbits2));
            f16* wdst = (ph == 0) ? HE : HV;
            const int wstr = (ph == 0) ? 2048 : 6144;
            const int woff = (ph == 0) ? 0 : (ph - 1) * 2048;

            // ---- GEMM with bias pre-loaded into accumulators
            f32x4 acc[2][4];
            #pragma unroll
            for (int g = 0; g < 4; ++g) {
                const float bg = bp[g * 128 + d];
                acc[0][g] = (f32x4)bg;
                acc[1][g] = (f32x4)bg;
            }
            // sub-loop 1: A from pa (stride sa), kk = 0..ksp-1
            #pragma unroll 1
            for (int kk = 0; kk < ksp; ++kk) {
                f16x8 A0 = *(const f16x8*)(pa + kk * 512);
                f16x8 A1 = *(const f16x8*)(pa + (sa + kk) * 512);
                #pragma unroll
                for (int g = 0; g < 4; ++g) {
                    f16x8 B = *(const f16x8*)(Wp + (size_t)((g * 8 + c) * nkk + kk) * 512 + l * 8);
                    acc[0][g] = MFh(A0, B, acc[0][g]);
                    acc[1][g] = MFh(A1, B, acc[1][g]);
                }
            }
            // sub-loop 2: A from pb (stride sb, base offset ob), kk = ksp..nkk-1
            #pragma unroll 1
            for (int kr = 0; kr < nkk - ksp; ++kr) {
                f16x8 A0 = *(const f16x8*)(pb + (ob + kr) * 512);
                f16x8 A1 = *(const f16x8*)(pb + (sb + ob + kr) * 512);
                #pragma unroll
                for (int g = 0; g < 4; ++g) {
                    f16x8 B = *(const f16x8*)(Wp + (size_t)((g * 8 + c) * nkk + ksp + kr) * 512 + l * 8);
                    acc[0][g] = MFh(A0, B, acc[0][g]);
                    acc[1][g] = MFh(A1, B, acc[1][g]);
                }
            }
            __syncthreads();   // WAR: all reads of this phase's write-tiles complete

            // ---- LSTM cell: state from ce (ph0) or cvG4 (ph>0)
            #pragma unroll
            for (int mt = 0; mt < 2; ++mt) {
                const size_t ci = cvBase + (size_t)((ph - 1) * 2 + mt) * 512;
                float cvv[4];
                if (ph == 0) {
                    #pragma unroll
                    for (int r = 0; r < 4; ++r) cvv[r] = ce[mt][r];
                } else if (it > 0) {
                    float4 t = cvG4[ci];
                    cvv[0] = t.x; cvv[1] = t.y; cvv[2] = t.z; cvv[3] = t.w;
                } else {
                    cvv[0] = cvv[1] = cvv[2] = cvv[3] = 0.0f;
                }
                #pragma unroll
                for (int r = 0; r < 4; ++r) {
                    if ((mb >> (mt * 4 + r)) & 1u) {
                        float gi = sigmoid_f(acc[mt][0][r]);
                        float gf = sigmoid_f(acc[mt][1][r]);
                        float gg = tanh_f(acc[mt][2][r]);
                        float go = sigmoid_f(acc[mt][3][r]);
                        float cn = gf * cvv[r] + gi * gg;
                        cvv[r] = cn;
                        wdst[wBase + mt * wstr + woff + r * 8] = (f16)(go * tanh_f(cn));
                    }
                }
                if (ph == 0) {
                    #pragma unroll
                    for (int r = 0; r < 4; ++r) ce[mt][r] = cvv[r];
                } else {
                    cvG4[ci] = make_float4(cvv[0], cvv[1], cvv[2], cvv[3]);
                }
            }
            if (ph == 0 || ph == 3) __syncthreads();   // RAW: HE ready / iter end
        }
    }

    // ---- write final h_v (fp16): [vertex][128] row-major
    for (int i = tid; i < 32 * 48; i += 512) {
        const int row = i / 48, seg = i % 48;
        *(f16x8*)&hvOut[(size_t)(e0 + row) * 384 + seg * 8] =
            *(const f16x8*)&HV[((row >> 4) * 12 + (seg >> 2)) * 512 + (seg & 3) * 128 + (row & 15) * 8];
    }
}

// logits = h_v @ out_w^T + out_b, swapped MFMA operands (A=out_w, B=h_v) -> each lane
// holds 4 consecutive vocab cols for one vertex -> float4 stores.
// r22: 64 VERTS/WAVE (Bv[4][4]) -> halves Ow L2 re-reads (3 GB -> 1.5 GB).
// 384 blocks x 256 thr -> 1536 waves x 64 = full coverage. W register dbuf.
// 48 KB LDS anchor -> 3-block model -> VGPR budget ~170 >= live ~130.
__global__ __launch_bounds__(256) void proj_kernel(
    const f16* __restrict__ hv, const f16* __restrict__ WF,
    const float* __restrict__ out_b, float* __restrict__ out)
{
    __shared__ char occ_pad[49152];
    const int tid = threadIdx.x, l = tid & 63;
    occ_pad[tid] = (char)tid;
    __syncthreads();
    {
        int keep = (int)occ_pad[(tid + 1) & 255];
        asm volatile("" :: "v"(keep));
    }

    const int wid = blockIdx.x * 4 + (tid >> 6);   // 0..1535
    const int v0 = wid * 64;
    const int lr = l & 15, lk = l >> 4;

    f16x8 Bv[4][4];
    #pragma unroll
    for (int vt = 0; vt < 4; ++vt)
        #pragma unroll
        for (int kk = 0; kk < 4; ++kk)
            Bv[vt][kk] = *(const f16x8*)(hv + (v0 + vt * 16 + lr) * D_ + kk * 32 + lk * 8);

    f16x8 Wc[4];
    #pragma unroll
    for (int kk = 0; kk < 4; ++kk)
        Wc[kk] = *(const f16x8*)(WF + (kk * 64 + l) * 8);

    #pragma unroll 1
    for (int nt = 0; nt < 125; ++nt) {
        f16x8 Wn[4];
        if (nt < 124) {
            #pragma unroll
            for (int kk = 0; kk < 4; ++kk)
                Wn[kk] = *(const f16x8*)(WF + (((nt + 1) * 4 + kk) * 64 + l) * 8);
        }
        f32x4 a0 = (f32x4)0.0f, a1 = (f32x4)0.0f, a2 = (f32x4)0.0f, a3 = (f32x4)0.0f;
        #pragma unroll
        for (int kk = 0; kk < 4; ++kk) {
            a0 = MFh(Wc[kk], Bv[0][kk], a0);
            a1 = MFh(Wc[kk], Bv[1][kk], a1);
            a2 = MFh(Wc[kk], Bv[2][kk], a2);
            a3 = MFh(Wc[kk], Bv[3][kk], a3);
        }
        const int n0 = nt * 16 + lk * 4;
        const float4 bb = *(const float4*)&out_b[n0];
        {
            const size_t v = (size_t)(v0 + lr);
            float4 o = make_float4(a0[0] + bb.x, a0[1] + bb.y, a0[2] + bb.z, a0[3] + bb.w);
            *(float4*)&out[v * VOCAB_ + n0] = o;
        }
        {
            const size_t v = (size_t)(v0 + 16 + lr);
            float4 o = make_float4(a1[0] + bb.x, a1[1] + bb.y, a1[2] + bb.z, a1[3] + bb.w);
            *(float4*)&out[v * VOCAB_ + n0] = o;
        }
        {
            const size_t v = (size_t)(v0 + 32 + lr);
            float4 o = make_float4(a2[0] + bb.x, a2[1] + bb.y, a2[2] + bb.z, a2[3] + bb.w);
            *(float4*)&out[v * VOCAB_ + n0] = o;
        }
        {
            const size_t v = (size_t)(v0 + 48 + lr);
            float4 o = make_float4(a3[0] + bb.x, a3[1] + bb.y, a3[2] + bb.z, a3[3] + bb.w);
            *(float4*)&out[v * VOCAB_ + n0] = o;
        }
        #pragma unroll
        for (int q = 0; q < 4; ++q) Wc[q] = Wn[q];
    }
}

extern "C" void kernel_launch(void* const* d_in, const int* in_sizes, int n_in,
                              void* d_out, int out_size, void* d_ws, size_t ws_size,
                              hipStream_t stream)
{
    const int*   x_v     = (const int*)  d_in[0];
    const void*  mask    = d_in[1];
    const float* emb     = (const float*)d_in[2];
    const float* eiw     = (const float*)d_in[3];
    const float* eib     = (const float*)d_in[4];
    const float* Wih_v2e = (const float*)d_in[5];
    const float* Whh_v2e = (const float*)d_in[6];
    const float* bih_v2e = (const float*)d_in[7];
    const float* bhh_v2e = (const float*)d_in[8];
    const float* Wih_e2v = (const float*)d_in[9];
    const float* Whh_e2v = (const float*)d_in[10];
    const float* bih_e2v = (const float*)d_in[11];
    const float* bhh_e2v = (const float*)d_in[12];
    const float* out_w   = (const float*)d_in[13];
    const float* out_b   = (const float*)d_in[14];
    float* out = (float*)d_out;

    // d_ws carve (~77.3 MB)
    char* ws = (char*)d_ws;
    f16*    hv   = (f16*)(ws);                  // 25165824 B
    f16*    WvF  = (f16*)(ws + 25165824);       // 524288
    f16*    WeF  = (f16*)(ws + 25690112);       // 786432
    f16*    OwF  = (f16*)(ws + 26476544);       // 512000
    float*  bv   = (float*)(ws + 26988544);     // 2048
    float*  be   = (float*)(ws + 26990592);     // 6144
    int*    flag = (int*)(ws + 26996736);       // 4
    float4* cvG4 = (float4*)(ws + 27000832);    // 50331648  [blk][(p*2+mt)][tid] float4

    hipMemsetAsync(flag, 0, 4, stream);
    detect_mask_kernel<<<16, 256, 0, stream>>>((const unsigned int*)mask, flag);
    prep_kernel<<<3568, 256, 0, stream>>>(Wih_v2e, Whh_v2e, bih_v2e, bhh_v2e,
                                          Wih_e2v, Whh_e2v, bih_e2v, bhh_e2v, out_w,
                                          WvF, WeF, OwF, bv, be);
    fused_kernel<<<E_CNT / 32, 512, 0, stream>>>(x_v, emb, eiw, eib,
                                                 WvF, WeF, bv, be,
                                                 mask, flag, cvG4, hv);
    proj_kernel<<<V_CNT / 256, 256, 0, stream>>>(hv, OwF, out_b, out);
}